// Round 2
// baseline (170.616 us; speedup 1.0000x reference)
//
#include <hip/hip_runtime.h>
#include <math.h>

#define T_FR 400
#define B_SZ 8
#define NH   32
#define HOP  240
#define PI_F 3.14159265358979323846f
#define TWO_PI_D 6.283185307179586476925287

enum { ACT_NONE=0, ACT_RELU=1, ACT_BNRELU=2, ACT_SIG=3, ACT_TANHH=4 };

// ---------------- per-(b,h) frame-level prefix scan (rev units) ----------------
__device__ inline double shfl_up_dbl(double x, int off)
{
    long long v = __double_as_longlong(x);
    int lo = (int)(v & 0xffffffffLL);
    int hi = (int)(v >> 32);
    lo = __shfl_up(lo, off);
    hi = __shfl_up(hi, off);
    return __longlong_as_double(((long long)hi << 32) | (unsigned int)(unsigned)lo);
}

__global__ __launch_bounds__(256)
void f0_scan_k(const float* __restrict__ f0, const float* __restrict__ voicing,
               float* __restrict__ inc_out, float* __restrict__ pref_out,
               unsigned int* __restrict__ wmax)
{
    // ---- block-redundant mean of f0 (12.8 KB, L2-hot) ----
    __shared__ double sred[256];
    const int tid = (int)threadIdx.x;
    double s = 0.0;
    for (int i = tid; i < B_SZ*T_FR; i += 256) s += (double)f0[i];
    sred[tid] = s;
    __syncthreads();
    for (int off = 128; off > 0; off >>= 1) {
        if (tid < off) sred[tid] += sred[tid + off];
        __syncthreads();
    }
    const float mean = (float)(sred[0] / (double)(B_SZ*T_FR));

    if (blockIdx.x == 0 && tid < B_SZ) wmax[tid] = 0u;

    // ---- per-wave scan: wid = (b,h) row ----
    const int wid  = (int)(blockIdx.x * 4 + (tid >> 6)); // 0..255
    const int lane = tid & 63;
    const int b = wid >> 5;
    const int h = wid & 31;
    const float n = (float)(h + 1);
    const float INV_SR = 1.0f / 22050.0f;

    float inc_loc[7];
    double local = 0.0;
    const int t0 = lane * 7;
    #pragma unroll
    for (int j = 0; j < 7; ++j) {
        int t = t0 + j;
        float iv = 0.f;
        if (t < T_FR) {
            float x  = f0[b*T_FR + t];
            float vv = voicing[b*T_FR + t];
            float midi = 440.0f * exp2f((x - 69.0f) / 12.0f);
            float fz = (mean < 0.f) ? expf(x) : ((mean < 50.f) ? midi : x);
            fz = fminf(fmaxf(fz, 50.f), 4000.f);
            fz = fz * vv + 100.f * (1.f - vv);
            iv = fminf(fz * n * INV_SR, 0.5f);   // rev units; clip(inc,-pi,pi)/2pi, inc>0
        }
        inc_loc[j] = iv;
        local += (double)iv;
    }
    local *= 240.0;   // whole-frame contribution (rev)

    double inc_sc = local;
    for (int off = 1; off < 64; off <<= 1) {
        double o = shfl_up_dbl(inc_sc, off);
        if (lane >= off) inc_sc += o;
    }
    double run = inc_sc - local;  // exclusive prefix (rev)

    #pragma unroll
    for (int j = 0; j < 7; ++j) {
        int t = t0 + j;
        if (t < T_FR) {
            inc_out[wid*T_FR + t]  = inc_loc[j];
            pref_out[wid*T_FR + t] = (float)fmod(run, 1.0);
            run += (double)inc_loc[j] * 240.0;
        }
    }
}

// ---------------- generic 3-tap conv1d, COPT cout per thread ----------------
template<int CIN1, int CIN2, int COPT, int ACT>
__global__ __launch_bounds__(64)
void conv3_k(const float* __restrict__ x1, const float* __restrict__ x2,
             const float* __restrict__ w, const float* __restrict__ bias,
             const float* __restrict__ g, const float* __restrict__ be,
             const float* __restrict__ mn, const float* __restrict__ vr,
             const float* __restrict__ voiced,
             float* __restrict__ y, int Cout)
{
    const int t   = (int)(blockIdx.x * 64 + threadIdx.x);
    const bool ok = (t < T_FR);
    const int tt  = ok ? t : 0;
    const int co0 = (int)blockIdx.y * COPT;
    const int b   = (int)blockIdx.z;
    const int CIN = CIN1 + CIN2;
    const bool hasm = ok && (t > 0);
    const bool hasp = ok && (t < T_FR - 1);

    float acc[COPT];
    #pragma unroll
    for (int j = 0; j < COPT; ++j) acc[j] = bias[co0 + j];

    {
        const float* xb = x1 + (size_t)b * CIN1 * T_FR + tt;
        #pragma unroll 4
        for (int ci = 0; ci < CIN1; ++ci) {
            float xm = hasm ? xb[ci*T_FR - 1] : 0.f;
            float xc = xb[ci*T_FR];
            float xp = hasp ? xb[ci*T_FR + 1] : 0.f;
            #pragma unroll
            for (int j = 0; j < COPT; ++j) {
                const float* wr = w + ((size_t)(co0 + j) * CIN + ci) * 3;
                acc[j] = fmaf(xm, wr[0], acc[j]);
                acc[j] = fmaf(xc, wr[1], acc[j]);
                acc[j] = fmaf(xp, wr[2], acc[j]);
            }
        }
    }
    if constexpr (CIN2 > 0) {
        const float* xb = x2 + (size_t)b * CIN2 * T_FR + tt;
        #pragma unroll 4
        for (int ci = 0; ci < CIN2; ++ci) {
            float xm = hasm ? xb[ci*T_FR - 1] : 0.f;
            float xc = xb[ci*T_FR];
            float xp = hasp ? xb[ci*T_FR + 1] : 0.f;
            #pragma unroll
            for (int j = 0; j < COPT; ++j) {
                const float* wr = w + ((size_t)(co0 + j) * CIN + (CIN1 + ci)) * 3;
                acc[j] = fmaf(xm, wr[0], acc[j]);
                acc[j] = fmaf(xc, wr[1], acc[j]);
                acc[j] = fmaf(xp, wr[2], acc[j]);
            }
        }
    }

    if (ok) {
        #pragma unroll
        for (int j = 0; j < COPT; ++j) {
            int co = co0 + j;
            float a = acc[j];
            float val;
            if (ACT == ACT_BNRELU) {
                float scale = g[co] * rsqrtf(vr[co] + 1e-5f);
                a = (a - mn[co]) * scale + be[co];
                val = fmaxf(a, 0.f);
            } else if (ACT == ACT_RELU) {
                val = fmaxf(a, 0.f);
            } else if (ACT == ACT_SIG) {
                float sg = 1.f / (1.f + expf(-a));
                val = sg * voiced[b*T_FR + t] + 1e-8f;
            } else if (ACT == ACT_TANHH) {
                val = 0.5f * tanhf(a);          // fold ph*pi/(2pi) = ph/2 (rev units)
            } else {
                val = a;
            }
            y[((size_t)b * Cout + co) * T_FR + t] = val;
        }
    }
}

// ---------------- harmonic synthesis: one block per (b,t) frame ----------------
__global__ __launch_bounds__(256)
void synth_k(const float* __restrict__ inc, const float* __restrict__ pref,
             const float* __restrict__ amps, const float* __restrict__ ph,
             float* __restrict__ wave, unsigned int* __restrict__ wmax)
{
    const int bi = (int)blockIdx.x;          // 0..3199
    const int b  = bi / T_FR;
    const int t  = bi - b * T_FR;
    const int k  = (int)threadIdx.x;         // sample within frame, valid < 240
    const float kf = (float)(k + 1);
    const int base = (b * NH) * T_FR + t;

    float acc = 0.f;
    #pragma unroll
    for (int h = 0; h < NH; ++h) {
        const int r = base + h * T_FR;       // wave-uniform address -> s_load
        float p0  = pref[r] + ph[r];
        float rev = fmaf(kf, inc[r], p0);
        rev = rev - floorf(rev);             // fract -> [0,1)
        acc = fmaf(amps[r], __builtin_amdgcn_sinf(rev), acc);  // v_sin (revolutions)
    }

    const bool valid = (k < HOP);
    if (valid) wave[b*(T_FR*HOP) + t*HOP + k] = acc;

    float a = valid ? fabsf(acc) : 0.f;
    #pragma unroll
    for (int off = 32; off > 0; off >>= 1) a = fmaxf(a, __shfl_down(a, off));
    __shared__ float sm4[4];
    const int lane = k & 63;
    const int wv   = k >> 6;
    if (lane == 0) sm4[wv] = a;
    __syncthreads();
    if (k == 0) {
        float m = fmaxf(fmaxf(sm4[0], sm4[1]), fmaxf(sm4[2], sm4[3]));
        atomicMax(&wmax[b], __float_as_uint(m));   // wave bits: |x| >= 0
    }
}

__global__ __launch_bounds__(256)
void norm_k(const float* __restrict__ wave, const unsigned int* __restrict__ wmax,
            float* __restrict__ out)
{
    const int s = (int)(blockIdx.x * 256 + threadIdx.x);
    const int b = s / (T_FR * HOP);
    float wm = fmaxf(__uint_as_float(wmax[b]), 1e-8f);
    out[s] = tanhf(wave[s] / wm);
}

// ---------------- launch ----------------
extern "C" void kernel_launch(void* const* d_in, const int* in_sizes, int n_in,
                              void* d_out, int out_size, void* d_ws, size_t ws_size,
                              hipStream_t stream)
{
    const float* mel  = (const float*)d_in[0];
    const float* f0   = (const float*)d_in[1];
    const float* voi  = (const float*)d_in[2];
    const float* w_f1 = (const float*)d_in[3];  const float* b_f1 = (const float*)d_in[4];
    const float* w_f2 = (const float*)d_in[5];  const float* b_f2 = (const float*)d_in[6];
    const float* w_a1 = (const float*)d_in[7];  const float* b_a1 = (const float*)d_in[8];
    const float* g1   = (const float*)d_in[9];  const float* be1  = (const float*)d_in[10];
    const float* m1   = (const float*)d_in[11]; const float* v1   = (const float*)d_in[12];
    const float* w_a2 = (const float*)d_in[13]; const float* b_a2 = (const float*)d_in[14];
    const float* g2   = (const float*)d_in[15]; const float* be2  = (const float*)d_in[16];
    const float* m2   = (const float*)d_in[17]; const float* v2   = (const float*)d_in[18];
    const float* w_a3 = (const float*)d_in[19]; const float* b_a3 = (const float*)d_in[20];
    const float* w_p1 = (const float*)d_in[21]; const float* b_p1 = (const float*)d_in[22];
    const float* w_p2 = (const float*)d_in[23]; const float* b_p2 = (const float*)d_in[24];

    float* wsf = (float*)d_ws;
    unsigned int* wmax = (unsigned int*)(wsf + 8);
    float* F1   = wsf + 16;                 // (8,16,400)
    float* F2   = F1   + 8*16*400;          // (8,16,400)
    float* H1   = F2   + 8*16*400;          // (8,128,400)
    float* H2   = H1   + 8*128*400;         // (8,128,400)
    float* AMP  = H2   + 8*128*400;         // (8,32,400)
    float* P1   = AMP  + 8*32*400;          // (8,64,400)
    float* PH   = P1   + 8*64*400;          // (8,32,400)  (tanh/2, rev units)
    float* INC  = PH   + 8*32*400;          // (8,32,400)  (rev units)
    float* PREF = INC  + 8*32*400;          // (8,32,400)  (rev units)
    float* WAVE = PREF + 8*32*400;          // (8,96000)

    f0_scan_k<<<64, 256, 0, stream>>>(f0, voi, INC, PREF, wmax);

    conv3_k<1,0,4,ACT_RELU><<<dim3(7,4,8), 64, 0, stream>>>(
        f0, nullptr, w_f1, b_f1, nullptr,nullptr,nullptr,nullptr, nullptr, F1, 16);
    conv3_k<16,0,4,ACT_RELU><<<dim3(7,4,8), 64, 0, stream>>>(
        F1, nullptr, w_f2, b_f2, nullptr,nullptr,nullptr,nullptr, nullptr, F2, 16);
    conv3_k<80,0,8,ACT_BNRELU><<<dim3(7,16,8), 64, 0, stream>>>(
        mel, nullptr, w_a1, b_a1, g1, be1, m1, v1, nullptr, H1, 128);
    conv3_k<128,0,8,ACT_BNRELU><<<dim3(7,16,8), 64, 0, stream>>>(
        H1, nullptr, w_a2, b_a2, g2, be2, m2, v2, nullptr, H2, 128);
    conv3_k<128,0,4,ACT_SIG><<<dim3(7,8,8), 64, 0, stream>>>(
        H2, nullptr, w_a3, b_a3, nullptr,nullptr,nullptr,nullptr, voi, AMP, 32);
    conv3_k<80,16,8,ACT_RELU><<<dim3(7,8,8), 64, 0, stream>>>(
        mel, F2, w_p1, b_p1, nullptr,nullptr,nullptr,nullptr, nullptr, P1, 64);
    conv3_k<64,0,4,ACT_TANHH><<<dim3(7,8,8), 64, 0, stream>>>(
        P1, nullptr, w_p2, b_p2, nullptr,nullptr,nullptr,nullptr, nullptr, PH, 32);

    synth_k<<<3200, 256, 0, stream>>>(INC, PREF, AMP, PH, WAVE, wmax);
    norm_k<<<3000, 256, 0, stream>>>(WAVE, wmax, (float*)d_out);
}

// Round 3
// 125.836 us; speedup vs baseline: 1.3559x; 1.3559x over previous
//
#include <hip/hip_runtime.h>
#include <math.h>

#define T_FR 400
#define B_SZ 8
#define NH   32
#define HOP  240
#define PI_F 3.14159265358979323846f

enum { ACT_NONE=0, ACT_RELU=1, ACT_BNRELU=2, ACT_SIG=3, ACT_TANHH=4 };

// ---------------- per-(b,h) frame-level prefix scan (rev units) ----------------
__device__ inline double shfl_up_dbl(double x, int off)
{
    long long v = __double_as_longlong(x);
    int lo = (int)(v & 0xffffffffLL);
    int hi = (int)(v >> 32);
    lo = __shfl_up(lo, off);
    hi = __shfl_up(hi, off);
    return __longlong_as_double(((long long)hi << 32) | (unsigned int)(unsigned)lo);
}

__global__ __launch_bounds__(256)
void f0_scan_k(const float* __restrict__ f0, const float* __restrict__ voicing,
               float* __restrict__ inc_out, float* __restrict__ pref_out)
{
    // ---- block-redundant mean of f0 (12.8 KB, L2-hot) ----
    __shared__ double sred[256];
    const int tid = (int)threadIdx.x;
    double s = 0.0;
    for (int i = tid; i < B_SZ*T_FR; i += 256) s += (double)f0[i];
    sred[tid] = s;
    __syncthreads();
    for (int off = 128; off > 0; off >>= 1) {
        if (tid < off) sred[tid] += sred[tid + off];
        __syncthreads();
    }
    const float mean = (float)(sred[0] / (double)(B_SZ*T_FR));

    // ---- per-wave scan: wid = (b,h) row ----
    const int wid  = (int)(blockIdx.x * 4 + (tid >> 6)); // 0..255
    const int lane = tid & 63;
    const int b = wid >> 5;
    const int h = wid & 31;
    const float n = (float)(h + 1);
    const float INV_SR = 1.0f / 22050.0f;

    float inc_loc[7];
    double local = 0.0;
    const int t0 = lane * 7;
    #pragma unroll
    for (int j = 0; j < 7; ++j) {
        int t = t0 + j;
        float iv = 0.f;
        if (t < T_FR) {
            float x  = f0[b*T_FR + t];
            float vv = voicing[b*T_FR + t];
            float midi = 440.0f * exp2f((x - 69.0f) / 12.0f);
            float fz = (mean < 0.f) ? expf(x) : ((mean < 50.f) ? midi : x);
            fz = fminf(fmaxf(fz, 50.f), 4000.f);
            fz = fz * vv + 100.f * (1.f - vv);
            iv = fminf(fz * n * INV_SR, 0.5f);   // rev units, inc >= 0
        }
        inc_loc[j] = iv;
        local += (double)iv;
    }
    local *= 240.0;

    double inc_sc = local;
    for (int off = 1; off < 64; off <<= 1) {
        double o = shfl_up_dbl(inc_sc, off);
        if (lane >= off) inc_sc += o;
    }
    double run = inc_sc - local;  // exclusive prefix (rev)

    #pragma unroll
    for (int j = 0; j < 7; ++j) {
        int t = t0 + j;
        if (t < T_FR) {
            inc_out[wid*T_FR + t]  = inc_loc[j];
            pref_out[wid*T_FR + t] = (float)fmod(run, 1.0);
            run += (double)inc_loc[j] * 240.0;
        }
    }
}

// ---------------- fused f1+f2 (16ch) conv chain, one block per batch ----------------
__global__ __launch_bounds__(256)
void fconv_k(const float* __restrict__ f0,
             const float* __restrict__ w1, const float* __restrict__ b1,
             const float* __restrict__ w2, const float* __restrict__ b2,
             float* __restrict__ F2out)
{
    const int b = (int)blockIdx.x;
    const int tid = (int)threadIdx.x;
    __shared__ float xrow[T_FR + 2];
    __shared__ float f1s[16][T_FR + 2];

    for (int i = tid; i < T_FR + 2; i += 256) {
        int t = i - 1;
        xrow[i] = (t >= 0 && t < T_FR) ? f0[b*T_FR + t] : 0.f;
    }
    if (tid < 16) { f1s[tid][0] = 0.f; f1s[tid][T_FR + 1] = 0.f; }
    __syncthreads();

    for (int i = tid; i < 16*T_FR; i += 256) {
        int co = i / T_FR, t = i - co*T_FR;
        float a = b1[co];
        a = fmaf(xrow[t],   w1[co*3+0], a);
        a = fmaf(xrow[t+1], w1[co*3+1], a);
        a = fmaf(xrow[t+2], w1[co*3+2], a);
        f1s[co][t+1] = fmaxf(a, 0.f);
    }
    __syncthreads();

    for (int i = tid; i < 16*T_FR; i += 256) {
        int co = i / T_FR, t = i - co*T_FR;
        float a = b2[co];
        #pragma unroll 4
        for (int ci = 0; ci < 16; ++ci) {
            const float* wr = w2 + (co*16 + ci)*3;
            a = fmaf(f1s[ci][t],   wr[0], a);
            a = fmaf(f1s[ci][t+1], wr[1], a);
            a = fmaf(f1s[ci][t+2], wr[2], a);
        }
        F2out[(b*16 + co)*T_FR + t] = fmaxf(a, 0.f);
    }
}

// ---------------- generic 3-tap conv1d, COPT cout per thread, 256-thr blocks ----------------
template<int CIN1, int CIN2, int COPT, int ACT>
__global__ __launch_bounds__(256)
void conv3_k(const float* __restrict__ x1, const float* __restrict__ x2,
             const float* __restrict__ w, const float* __restrict__ bias,
             const float* __restrict__ g, const float* __restrict__ be,
             const float* __restrict__ mn, const float* __restrict__ vr,
             const float* __restrict__ voiced,
             float* __restrict__ y, int Cout)
{
    const int t = (int)(blockIdx.x * 256 + threadIdx.x);
    // whole-wave early exit for the tail
    if ((int)(blockIdx.x * 256 + (threadIdx.x & ~63u)) >= T_FR) return;
    const bool ok = (t < T_FR);
    const int tt  = ok ? t : 0;
    const int co0 = (int)blockIdx.y * COPT;
    const int b   = (int)blockIdx.z;
    const int CIN = CIN1 + CIN2;
    const bool hasm = ok && (t > 0);
    const bool hasp = ok && (t < T_FR - 1);

    float acc[COPT];
    #pragma unroll
    for (int j = 0; j < COPT; ++j) acc[j] = bias[co0 + j];

    {
        const float* xb = x1 + (size_t)b * CIN1 * T_FR + tt;
        #pragma unroll 4
        for (int ci = 0; ci < CIN1; ++ci) {
            float xm = hasm ? xb[ci*T_FR - 1] : 0.f;
            float xc = xb[ci*T_FR];
            float xp = hasp ? xb[ci*T_FR + 1] : 0.f;
            #pragma unroll
            for (int j = 0; j < COPT; ++j) {
                const float* wr = w + ((size_t)(co0 + j) * CIN + ci) * 3;
                acc[j] = fmaf(xm, wr[0], acc[j]);
                acc[j] = fmaf(xc, wr[1], acc[j]);
                acc[j] = fmaf(xp, wr[2], acc[j]);
            }
        }
    }
    if constexpr (CIN2 > 0) {
        const float* xb = x2 + (size_t)b * CIN2 * T_FR + tt;
        #pragma unroll 4
        for (int ci = 0; ci < CIN2; ++ci) {
            float xm = hasm ? xb[ci*T_FR - 1] : 0.f;
            float xc = xb[ci*T_FR];
            float xp = hasp ? xb[ci*T_FR + 1] : 0.f;
            #pragma unroll
            for (int j = 0; j < COPT; ++j) {
                const float* wr = w + ((size_t)(co0 + j) * CIN + (CIN1 + ci)) * 3;
                acc[j] = fmaf(xm, wr[0], acc[j]);
                acc[j] = fmaf(xc, wr[1], acc[j]);
                acc[j] = fmaf(xp, wr[2], acc[j]);
            }
        }
    }

    if (ok) {
        #pragma unroll
        for (int j = 0; j < COPT; ++j) {
            int co = co0 + j;
            float a = acc[j];
            float val;
            if (ACT == ACT_BNRELU) {
                float scale = g[co] * rsqrtf(vr[co] + 1e-5f);
                a = (a - mn[co]) * scale + be[co];
                val = fmaxf(a, 0.f);
            } else if (ACT == ACT_RELU) {
                val = fmaxf(a, 0.f);
            } else if (ACT == ACT_SIG) {
                float sg = 1.f / (1.f + expf(-a));
                val = sg * voiced[b*T_FR + t] + 1e-8f;
            } else if (ACT == ACT_TANHH) {
                val = 0.5f * tanhf(a);          // ph*pi in rev units = tanh/2
            } else {
                val = a;
            }
            y[((size_t)b * Cout + co) * T_FR + t] = val;
        }
    }
}

// ---------------- harmonic synthesis: block per frame, LDS param table ----------------
__global__ __launch_bounds__(256)
void synth_k(const float* __restrict__ inc, const float* __restrict__ pref,
             const float* __restrict__ amps, const float* __restrict__ ph,
             float* __restrict__ wave, float* __restrict__ bmax)
{
    const int bi = (int)blockIdx.x;          // 0..3199 = b*400+t
    const int b  = bi / T_FR;
    const int t  = bi - b * T_FR;
    const int tid = (int)threadIdx.x;

    __shared__ float4 sp[NH];                // {inc, pref, amp, ph} per harmonic
    if (tid < 128) {
        const int arr = tid >> 5;
        const int h   = tid & 31;
        const float* src = (arr == 0) ? inc : (arr == 1) ? pref : (arr == 2) ? amps : ph;
        ((float*)&sp[h])[arr] = src[(b*NH + h)*T_FR + t];
    }
    __syncthreads();

    const float kf = (float)(tid + 1);
    float acc = 0.f;
    #pragma unroll 8
    for (int h = 0; h < NH; ++h) {
        float4 p = sp[h];                    // same-address broadcast: free
        float rev = fmaf(kf, p.x, p.y + p.w);
        rev -= floorf(rev);
        acc = fmaf(p.z, __builtin_amdgcn_sinf(rev), acc);
    }

    const bool valid = (tid < HOP);
    if (valid) wave[(size_t)bi * HOP + tid] = acc;

    float a = valid ? fabsf(acc) : 0.f;
    #pragma unroll
    for (int off = 32; off > 0; off >>= 1) a = fmaxf(a, __shfl_down(a, off));
    __shared__ float sm4[4];
    if ((tid & 63) == 0) sm4[tid >> 6] = a;
    __syncthreads();
    if (tid == 0)
        bmax[bi] = fmaxf(fmaxf(sm4[0], sm4[1]), fmaxf(sm4[2], sm4[3]));
}

// ---------------- normalize: per-b max (redundant block reduce) + tanh ----------------
__global__ __launch_bounds__(256)
void norm_k(const float* __restrict__ wave, const float* __restrict__ bmax,
            float* __restrict__ out)
{
    const int b   = (int)blockIdx.y;
    const int tid = (int)threadIdx.x;

    float m = 0.f;
    for (int i = tid; i < T_FR; i += 256) m = fmaxf(m, bmax[b*T_FR + i]);
    #pragma unroll
    for (int off = 32; off > 0; off >>= 1) m = fmaxf(m, __shfl_down(m, off));
    __shared__ float sm4[4];
    __shared__ float wm_s;
    if ((tid & 63) == 0) sm4[tid >> 6] = m;
    __syncthreads();
    if (tid == 0)
        wm_s = fmaxf(fmaxf(fmaxf(sm4[0], sm4[1]), fmaxf(sm4[2], sm4[3])), 1e-8f);
    __syncthreads();
    const float inv_wm = 1.f / wm_s;

    const int s0 = (int)blockIdx.x * 1024 + tid;
    #pragma unroll
    for (int j = 0; j < 4; ++j) {
        int s = s0 + j * 256;
        if (s < T_FR*HOP) {
            float v = wave[(size_t)b * (T_FR*HOP) + s];
            out[(size_t)b * (T_FR*HOP) + s] = tanhf(v * inv_wm);
        }
    }
}

// ---------------- launch ----------------
extern "C" void kernel_launch(void* const* d_in, const int* in_sizes, int n_in,
                              void* d_out, int out_size, void* d_ws, size_t ws_size,
                              hipStream_t stream)
{
    const float* mel  = (const float*)d_in[0];
    const float* f0   = (const float*)d_in[1];
    const float* voi  = (const float*)d_in[2];
    const float* w_f1 = (const float*)d_in[3];  const float* b_f1 = (const float*)d_in[4];
    const float* w_f2 = (const float*)d_in[5];  const float* b_f2 = (const float*)d_in[6];
    const float* w_a1 = (const float*)d_in[7];  const float* b_a1 = (const float*)d_in[8];
    const float* g1   = (const float*)d_in[9];  const float* be1  = (const float*)d_in[10];
    const float* m1   = (const float*)d_in[11]; const float* v1   = (const float*)d_in[12];
    const float* w_a2 = (const float*)d_in[13]; const float* b_a2 = (const float*)d_in[14];
    const float* g2   = (const float*)d_in[15]; const float* be2  = (const float*)d_in[16];
    const float* m2   = (const float*)d_in[17]; const float* v2   = (const float*)d_in[18];
    const float* w_a3 = (const float*)d_in[19]; const float* b_a3 = (const float*)d_in[20];
    const float* w_p1 = (const float*)d_in[21]; const float* b_p1 = (const float*)d_in[22];
    const float* w_p2 = (const float*)d_in[23]; const float* b_p2 = (const float*)d_in[24];

    float* wsf = (float*)d_ws;
    float* BMAX = wsf;                      // 3200
    float* F2   = BMAX + 3200;              // (8,16,400)
    float* H1   = F2   + 8*16*400;          // (8,128,400)
    float* H2   = H1   + 8*128*400;         // (8,128,400)
    float* AMP  = H2   + 8*128*400;         // (8,32,400)
    float* P1   = AMP  + 8*32*400;          // (8,64,400)
    float* PH   = P1   + 8*64*400;          // (8,32,400)  tanh/2, rev
    float* INC  = PH   + 8*32*400;          // (8,32,400)  rev
    float* PREF = INC  + 8*32*400;          // (8,32,400)  rev
    float* WAVE = PREF + 8*32*400;          // (8,96000)

    f0_scan_k<<<64, 256, 0, stream>>>(f0, voi, INC, PREF);
    fconv_k<<<8, 256, 0, stream>>>(f0, w_f1, b_f1, w_f2, b_f2, F2);

    conv3_k<80,0,4,ACT_BNRELU><<<dim3(2,32,8), 256, 0, stream>>>(
        mel, nullptr, w_a1, b_a1, g1, be1, m1, v1, nullptr, H1, 128);
    conv3_k<128,0,4,ACT_BNRELU><<<dim3(2,32,8), 256, 0, stream>>>(
        H1, nullptr, w_a2, b_a2, g2, be2, m2, v2, nullptr, H2, 128);
    conv3_k<128,0,4,ACT_SIG><<<dim3(2,8,8), 256, 0, stream>>>(
        H2, nullptr, w_a3, b_a3, nullptr,nullptr,nullptr,nullptr, voi, AMP, 32);
    conv3_k<80,16,4,ACT_RELU><<<dim3(2,16,8), 256, 0, stream>>>(
        mel, F2, w_p1, b_p1, nullptr,nullptr,nullptr,nullptr, nullptr, P1, 64);
    conv3_k<64,0,4,ACT_TANHH><<<dim3(2,8,8), 256, 0, stream>>>(
        P1, nullptr, w_p2, b_p2, nullptr,nullptr,nullptr,nullptr, nullptr, PH, 32);

    synth_k<<<3200, 256, 0, stream>>>(INC, PREF, AMP, PH, WAVE, BMAX);
    norm_k<<<dim3(94, 8), 256, 0, stream>>>(WAVE, BMAX, (float*)d_out);
}

// Round 4
// 78.587 us; speedup vs baseline: 2.1710x; 1.6012x over previous
//
#include <hip/hip_runtime.h>
#include <math.h>

#define T_FR 400
#define B_SZ 8
#define NH   32
#define HOP  240

enum { ACT_NONE=0, ACT_RELU=1, ACT_BNRELU=2, ACT_SIG=3, ACT_TANHH=4 };

__device__ __forceinline__ float fast_tanh(float x)
{
    x = fminf(fmaxf(x, -9.f), 9.f);
    float e = __expf(2.f * x);
    return (e - 1.f) / (e + 1.f);
}

// ---------------- double shuffle helper ----------------
__device__ inline double shfl_up_dbl(double x, int off)
{
    long long v = __double_as_longlong(x);
    int lo = (int)(v & 0xffffffffLL);
    int hi = (int)(v >> 32);
    lo = __shfl_up(lo, off);
    hi = __shfl_up(hi, off);
    return __longlong_as_double(((long long)hi << 32) | (unsigned int)(unsigned)lo);
}

// ---------------- generic 3-tap conv: 2 consecutive t per thread, COPT couts ----------------
template<int CIN1, int CIN2, int COPT, int ACT>
__device__ __forceinline__ void conv_dev(
    int bi, const float* __restrict__ x1, const float* __restrict__ x2,
    const float* __restrict__ w, const float* __restrict__ bias,
    const float* __restrict__ g, const float* __restrict__ be,
    const float* __restrict__ mn, const float* __restrict__ vr,
    const float* __restrict__ voiced,
    float* __restrict__ y, int Cout)
{
    const int CIN = CIN1 + CIN2;
    const int nCoT = Cout / COPT;
    const int b   = bi / nCoT;
    const int co0 = (bi - b * nCoT) * COPT;
    const int tid = (int)threadIdx.x;
    if (tid >= 200) return;
    const int t0 = tid * 2;                    // t0, t0+1 both < 400
    const bool has_m = (t0 > 0);
    const bool has_q = (t0 + 2 < T_FR);

    float acc[COPT][2];
    #pragma unroll
    for (int j = 0; j < COPT; ++j) { float bv = bias[co0 + j]; acc[j][0] = bv; acc[j][1] = bv; }

    {
        const float* xb = x1 + ((size_t)b * CIN1) * T_FR;
        #pragma unroll 4
        for (int ci = 0; ci < CIN1; ++ci) {
            const float* xr = xb + ci * T_FR;
            float xm = has_m ? xr[t0 - 1] : 0.f;
            float xc = xr[t0];
            float xp = xr[t0 + 1];
            float xq = has_q ? xr[t0 + 2] : 0.f;
            #pragma unroll
            for (int j = 0; j < COPT; ++j) {
                const float* wr = w + ((size_t)(co0 + j) * CIN + ci) * 3;
                float w0 = wr[0], w1 = wr[1], w2 = wr[2];
                acc[j][0] = fmaf(xm, w0, fmaf(xc, w1, fmaf(xp, w2, acc[j][0])));
                acc[j][1] = fmaf(xc, w0, fmaf(xp, w1, fmaf(xq, w2, acc[j][1])));
            }
        }
    }
    if constexpr (CIN2 > 0) {
        const float* xb = x2 + ((size_t)b * CIN2) * T_FR;
        #pragma unroll 4
        for (int ci = 0; ci < CIN2; ++ci) {
            const float* xr = xb + ci * T_FR;
            float xm = has_m ? xr[t0 - 1] : 0.f;
            float xc = xr[t0];
            float xp = xr[t0 + 1];
            float xq = has_q ? xr[t0 + 2] : 0.f;
            #pragma unroll
            for (int j = 0; j < COPT; ++j) {
                const float* wr = w + ((size_t)(co0 + j) * CIN + CIN1 + ci) * 3;
                float w0 = wr[0], w1 = wr[1], w2 = wr[2];
                acc[j][0] = fmaf(xm, w0, fmaf(xc, w1, fmaf(xp, w2, acc[j][0])));
                acc[j][1] = fmaf(xc, w0, fmaf(xp, w1, fmaf(xq, w2, acc[j][1])));
            }
        }
    }

    float2 vo;
    if (ACT == ACT_SIG) vo = *(const float2*)(voiced + (size_t)b * T_FR + t0);

    #pragma unroll
    for (int j = 0; j < COPT; ++j) {
        int co = co0 + j;
        float v0, v1;
        if (ACT == ACT_BNRELU) {
            float scale = g[co] * rsqrtf(vr[co] + 1e-5f);
            float sh = be[co] - mn[co] * scale;
            v0 = fmaxf(fmaf(acc[j][0], scale, sh), 0.f);
            v1 = fmaxf(fmaf(acc[j][1], scale, sh), 0.f);
        } else if (ACT == ACT_RELU) {
            v0 = fmaxf(acc[j][0], 0.f);
            v1 = fmaxf(acc[j][1], 0.f);
        } else if (ACT == ACT_SIG) {
            v0 = vo.x / (1.f + __expf(-acc[j][0])) + 1e-8f;
            v1 = vo.y / (1.f + __expf(-acc[j][1])) + 1e-8f;
        } else if (ACT == ACT_TANHH) {
            v0 = 0.5f * fast_tanh(acc[j][0]);   // ph*pi in rev units = tanh/2
            v1 = 0.5f * fast_tanh(acc[j][1]);
        } else {
            v0 = acc[j][0]; v1 = acc[j][1];
        }
        float2 st = {v0, v1};
        *(float2*)(y + ((size_t)b * Cout + co) * T_FR + t0) = st;
    }
}

// ---------------- K1: f0_scan (64) | fconv tiles (40) | conv_a1 (256) ----------------
__global__ __launch_bounds__(256)
void k1(const float* __restrict__ f0, const float* __restrict__ voi,
        const float* __restrict__ mel,
        const float* __restrict__ w_f1, const float* __restrict__ b_f1,
        const float* __restrict__ w_f2, const float* __restrict__ b_f2,
        const float* __restrict__ w_a1, const float* __restrict__ b_a1,
        const float* __restrict__ g1, const float* __restrict__ be1,
        const float* __restrict__ m1, const float* __restrict__ v1,
        float* __restrict__ INC, float* __restrict__ PREF,
        float* __restrict__ F2, float* __restrict__ H1)
{
    const int blk = (int)blockIdx.x;
    const int tid = (int)threadIdx.x;

    if (blk < 64) {
        // ---- f0 scan: mean (block-redundant) + per-(b,h) prefix ----
        __shared__ double sred[256];
        double s = 0.0;
        for (int i = tid; i < B_SZ*T_FR; i += 256) s += (double)f0[i];
        sred[tid] = s;
        __syncthreads();
        for (int off = 128; off > 0; off >>= 1) {
            if (tid < off) sred[tid] += sred[tid + off];
            __syncthreads();
        }
        const float mean = (float)(sred[0] / (double)(B_SZ*T_FR));

        const int wid  = blk * 4 + (tid >> 6);
        const int lane = tid & 63;
        const int b = wid >> 5;
        const int h = wid & 31;
        const float n = (float)(h + 1);
        const float INV_SR = 1.0f / 22050.0f;

        float inc_loc[7];
        double local = 0.0;
        const int t0 = lane * 7;
        #pragma unroll
        for (int j = 0; j < 7; ++j) {
            int t = t0 + j;
            float iv = 0.f;
            if (t < T_FR) {
                float x  = f0[b*T_FR + t];
                float vv = voi[b*T_FR + t];
                float midi = 440.0f * exp2f((x - 69.0f) / 12.0f);
                float fz = (mean < 0.f) ? __expf(x) : ((mean < 50.f) ? midi : x);
                fz = fminf(fmaxf(fz, 50.f), 4000.f);
                fz = fz * vv + 100.f * (1.f - vv);
                iv = fminf(fz * n * INV_SR, 0.5f);   // rev units, >= 0
            }
            inc_loc[j] = iv;
            local += (double)iv;
        }
        local *= 240.0;

        double inc_sc = local;
        for (int off = 1; off < 64; off <<= 1) {
            double o = shfl_up_dbl(inc_sc, off);
            if (lane >= off) inc_sc += o;
        }
        double run = inc_sc - local;

        #pragma unroll
        for (int j = 0; j < 7; ++j) {
            int t = t0 + j;
            if (t < T_FR) {
                INC[wid*T_FR + t]  = inc_loc[j];
                PREF[wid*T_FR + t] = (float)fmod(run, 1.0);
                run += (double)inc_loc[j] * 240.0;
            }
        }
    } else if (blk < 104) {
        // ---- fused f1+f2 chain, t-tile of 80 ----
        const int tb = blk - 64;
        const int b  = tb / 5;
        const int tg = (tb - b * 5) * 80;     // tile start
        __shared__ float xrow[84];            // global t = tg-2 .. tg+81
        __shared__ float f1s[16][84];         // u = tau-(tg-1), tau = tg-1 .. tg+80

        if (tid < 84) {
            int t = tg - 2 + tid;
            xrow[tid] = (t >= 0 && t < T_FR) ? f0[b*T_FR + t] : 0.f;
        }
        __syncthreads();

        for (int i = tid; i < 16*82; i += 256) {
            int co = i / 82, u = i - co*82;
            int tau = tg - 1 + u;
            float a = b_f1[co];
            a = fmaf(xrow[u],   w_f1[co*3+0], a);
            a = fmaf(xrow[u+1], w_f1[co*3+1], a);
            a = fmaf(xrow[u+2], w_f1[co*3+2], a);
            f1s[co][u] = (tau >= 0 && tau < T_FR) ? fmaxf(a, 0.f) : 0.f;
        }
        __syncthreads();

        for (int i = tid; i < 16*80; i += 256) {
            int co = i / 80, v = i - co*80;
            float a = b_f2[co];
            #pragma unroll 4
            for (int ci = 0; ci < 16; ++ci) {
                const float* wr = w_f2 + (co*16 + ci)*3;
                a = fmaf(f1s[ci][v],   wr[0], a);
                a = fmaf(f1s[ci][v+1], wr[1], a);
                a = fmaf(f1s[ci][v+2], wr[2], a);
            }
            F2[(b*16 + co)*T_FR + tg + v] = fmaxf(a, 0.f);
        }
    } else {
        conv_dev<80,0,4,ACT_BNRELU>(blk - 104, mel, nullptr, w_a1, b_a1,
                                    g1, be1, m1, v1, nullptr, H1, 128);
    }
}

// ---------------- K2: conv_a2 (256) | conv_p1 (128) ----------------
__global__ __launch_bounds__(256)
void k2(const float* __restrict__ H1, const float* __restrict__ mel,
        const float* __restrict__ F2,
        const float* __restrict__ w_a2, const float* __restrict__ b_a2,
        const float* __restrict__ g2, const float* __restrict__ be2,
        const float* __restrict__ m2, const float* __restrict__ v2,
        const float* __restrict__ w_p1, const float* __restrict__ b_p1,
        float* __restrict__ H2, float* __restrict__ P1)
{
    const int blk = (int)blockIdx.x;
    if (blk < 256)
        conv_dev<128,0,4,ACT_BNRELU>(blk, H1, nullptr, w_a2, b_a2,
                                     g2, be2, m2, v2, nullptr, H2, 128);
    else
        conv_dev<80,16,4,ACT_RELU>(blk - 256, mel, F2, w_p1, b_p1,
                                   nullptr, nullptr, nullptr, nullptr, nullptr, P1, 64);
}

// ---------------- K3: conv_a3 (64) | conv_p2 (64) ----------------
__global__ __launch_bounds__(256)
void k3(const float* __restrict__ H2, const float* __restrict__ P1,
        const float* __restrict__ voi,
        const float* __restrict__ w_a3, const float* __restrict__ b_a3,
        const float* __restrict__ w_p2, const float* __restrict__ b_p2,
        float* __restrict__ AMP, float* __restrict__ PH)
{
    const int blk = (int)blockIdx.x;
    if (blk < 64)
        conv_dev<128,0,4,ACT_SIG>(blk, H2, nullptr, w_a3, b_a3,
                                  nullptr, nullptr, nullptr, nullptr, voi, AMP, 32);
    else
        conv_dev<64,0,4,ACT_TANHH>(blk - 64, P1, nullptr, w_p2, b_p2,
                                   nullptr, nullptr, nullptr, nullptr, nullptr, PH, 32);
}

// ---------------- synth: block per (b,t) frame, LDS param table ----------------
__global__ __launch_bounds__(256)
void synth_k(const float* __restrict__ inc, const float* __restrict__ pref,
             const float* __restrict__ amps, const float* __restrict__ ph,
             float* __restrict__ wave, float* __restrict__ bmax)
{
    const int bi = (int)blockIdx.x;          // b*400+t
    const int b  = bi / T_FR;
    const int t  = bi - b * T_FR;
    const int tid = (int)threadIdx.x;

    __shared__ float4 sp[NH];                // {inc, pref, amp, ph}
    if (tid < 128) {
        const int arr = tid >> 5;
        const int h   = tid & 31;
        const float* src = (arr == 0) ? inc : (arr == 1) ? pref : (arr == 2) ? amps : ph;
        ((float*)&sp[h])[arr] = src[(b*NH + h)*T_FR + t];
    }
    __syncthreads();

    const float kf = (float)(tid + 1);
    float acc = 0.f;
    #pragma unroll 8
    for (int h = 0; h < NH; ++h) {
        float4 p = sp[h];
        float rev = fmaf(kf, p.x, p.y + p.w);
        rev -= floorf(rev);
        acc = fmaf(p.z, __builtin_amdgcn_sinf(rev), acc);
    }

    const bool valid = (tid < HOP);
    if (valid) wave[(size_t)bi * HOP + tid] = acc;

    float a = valid ? fabsf(acc) : 0.f;
    #pragma unroll
    for (int off = 32; off > 0; off >>= 1) a = fmaxf(a, __shfl_down(a, off));
    __shared__ float sm4[4];
    if ((tid & 63) == 0) sm4[tid >> 6] = a;
    __syncthreads();
    if (tid == 0)
        bmax[bi] = fmaxf(fmaxf(sm4[0], sm4[1]), fmaxf(sm4[2], sm4[3]));
}

// ---------------- normalize: per-b max (block-redundant) + fast tanh ----------------
__global__ __launch_bounds__(256)
void norm_k(const float* __restrict__ wave, const float* __restrict__ bmax,
            float* __restrict__ out)
{
    const int b   = (int)blockIdx.y;
    const int tid = (int)threadIdx.x;

    float m = 0.f;
    for (int i = tid; i < T_FR; i += 256) m = fmaxf(m, bmax[b*T_FR + i]);
    #pragma unroll
    for (int off = 32; off > 0; off >>= 1) m = fmaxf(m, __shfl_down(m, off));
    __shared__ float sm4[4];
    __shared__ float wm_s;
    if ((tid & 63) == 0) sm4[tid >> 6] = m;
    __syncthreads();
    if (tid == 0)
        wm_s = fmaxf(fmaxf(fmaxf(sm4[0], sm4[1]), fmaxf(sm4[2], sm4[3])), 1e-8f);
    __syncthreads();
    const float inv_wm = 1.f / wm_s;

    const int s0 = (int)blockIdx.x * 1024 + tid;
    #pragma unroll
    for (int j = 0; j < 4; ++j) {
        int s = s0 + j * 256;
        if (s < T_FR*HOP) {
            float v = wave[(size_t)b * (T_FR*HOP) + s] * inv_wm;   // in [-1,1]
            float e = __expf(2.f * v);
            out[(size_t)b * (T_FR*HOP) + s] = (e - 1.f) / (e + 1.f);
        }
    }
}

// ---------------- launch ----------------
extern "C" void kernel_launch(void* const* d_in, const int* in_sizes, int n_in,
                              void* d_out, int out_size, void* d_ws, size_t ws_size,
                              hipStream_t stream)
{
    const float* mel  = (const float*)d_in[0];
    const float* f0   = (const float*)d_in[1];
    const float* voi  = (const float*)d_in[2];
    const float* w_f1 = (const float*)d_in[3];  const float* b_f1 = (const float*)d_in[4];
    const float* w_f2 = (const float*)d_in[5];  const float* b_f2 = (const float*)d_in[6];
    const float* w_a1 = (const float*)d_in[7];  const float* b_a1 = (const float*)d_in[8];
    const float* g1   = (const float*)d_in[9];  const float* be1  = (const float*)d_in[10];
    const float* m1   = (const float*)d_in[11]; const float* v1   = (const float*)d_in[12];
    const float* w_a2 = (const float*)d_in[13]; const float* b_a2 = (const float*)d_in[14];
    const float* g2   = (const float*)d_in[15]; const float* be2  = (const float*)d_in[16];
    const float* m2   = (const float*)d_in[17]; const float* v2   = (const float*)d_in[18];
    const float* w_a3 = (const float*)d_in[19]; const float* b_a3 = (const float*)d_in[20];
    const float* w_p1 = (const float*)d_in[21]; const float* b_p1 = (const float*)d_in[22];
    const float* w_p2 = (const float*)d_in[23]; const float* b_p2 = (const float*)d_in[24];

    float* wsf = (float*)d_ws;
    float* BMAX = wsf;                      // 3200
    float* F2   = BMAX + 3200;              // (8,16,400)
    float* H1   = F2   + 8*16*400;          // (8,128,400)
    float* H2   = H1   + 8*128*400;         // (8,128,400)
    float* AMP  = H2   + 8*128*400;         // (8,32,400)
    float* P1   = AMP  + 8*32*400;          // (8,64,400)
    float* PH   = P1   + 8*64*400;          // (8,32,400)  tanh/2, rev
    float* INC  = PH   + 8*32*400;          // (8,32,400)  rev
    float* PREF = INC  + 8*32*400;          // (8,32,400)  rev
    float* WAVE = PREF + 8*32*400;          // (8,96000)

    k1<<<360, 256, 0, stream>>>(f0, voi, mel, w_f1, b_f1, w_f2, b_f2,
                                w_a1, b_a1, g1, be1, m1, v1,
                                INC, PREF, F2, H1);
    k2<<<384, 256, 0, stream>>>(H1, mel, F2, w_a2, b_a2, g2, be2, m2, v2,
                                w_p1, b_p1, H2, P1);
    k3<<<128, 256, 0, stream>>>(H2, P1, voi, w_a3, b_a3, w_p2, b_p2, AMP, PH);
    synth_k<<<3200, 256, 0, stream>>>(INC, PREF, AMP, PH, WAVE, BMAX);
    norm_k<<<dim3(94, 8), 256, 0, stream>>>(WAVE, BMAX, (float*)d_out);
}